// Round 2
// 280.529 us; speedup vs baseline: 1.0556x; 1.0556x over previous
//
#include <hip/hip_runtime.h>
#include <hip/hip_fp16.h>

#define D 128
#define SCAN_B 256
#define HLD 136   // LDS row stride (halfs) for fused-FC staging; 136*2=272 B keeps uint4 alignment

typedef __attribute__((ext_vector_type(8))) _Float16 f16x8;
typedef __attribute__((ext_vector_type(4))) float f32x4;

// ---- degree count ----
__global__ void count_kernel(const int* __restrict__ ei, int E, int* __restrict__ cnt) {
    int t = blockIdx.x * blockDim.x + threadIdx.x;
    if (t < E) atomicAdd(&cnt[ei[E + t]], 1);
}

// ---- hierarchical exclusive scan ----
__global__ void scan_pass1(const int* __restrict__ cnt, int* __restrict__ rs,
                           int* __restrict__ bsum, int N) {
    __shared__ int lds[SCAN_B];
    int tid = threadIdx.x;
    int i = blockIdx.x * SCAN_B + tid;
    int v = (i < N) ? cnt[i] : 0;
    lds[tid] = v;
    __syncthreads();
    for (int o = 1; o < SCAN_B; o <<= 1) {
        int t = (tid >= o) ? lds[tid - o] : 0;
        __syncthreads();
        lds[tid] += t;
        __syncthreads();
    }
    if (i < N) rs[i] = lds[tid] - v;
    if (tid == SCAN_B - 1) bsum[blockIdx.x] = lds[tid];
}

__global__ void scan_pass2(int* __restrict__ bsum, int nb) {
    __shared__ int lds[SCAN_B];
    int tid = threadIdx.x;
    int v = (tid < nb) ? bsum[tid] : 0;
    lds[tid] = v;
    __syncthreads();
    for (int o = 1; o < SCAN_B; o <<= 1) {
        int t = (tid >= o) ? lds[tid - o] : 0;
        __syncthreads();
        lds[tid] += t;
        __syncthreads();
    }
    if (tid < nb) bsum[tid] = lds[tid] - v;
}

__global__ void scan_pass3(int* __restrict__ rs, int* __restrict__ cursor,
                           const int* __restrict__ bsum, const int* __restrict__ cnt,
                           float* __restrict__ inv, int N) {
    int i = blockIdx.x * SCAN_B + threadIdx.x;
    if (i < N) {
        int v = rs[i] + bsum[blockIdx.x];
        rs[i] = v;
        cursor[i] = v;
        inv[i] = 1.0f / (float)max(cnt[i], 1);
    }
}

__global__ void fill_kernel(const int* __restrict__ ei, int E,
                            int* __restrict__ cursor, int* __restrict__ csr) {
    int e = blockIdx.x * blockDim.x + threadIdx.x;
    if (e < E) {
        int src = ei[e], dst = ei[E + e];
        int pos = atomicAdd(&cursor[dst], 1);
        csr[pos] = src;
    }
}

// ---- fp32 -> fp16 (hi only) row cache for the gather ----
__global__ void cvt_half_kernel(const float* __restrict__ x, __half* __restrict__ xh, int n8) {
    int i = blockIdx.x * blockDim.x + threadIdx.x;
    if (i >= n8) return;
    const float4* x4 = (const float4*)x;
    float4 a = x4[2 * i], b = x4[2 * i + 1];
    __half2 h0 = __floats2half2_rn(a.x, a.y);
    __half2 h1 = __floats2half2_rn(a.z, a.w);
    __half2 h2 = __floats2half2_rn(b.x, b.y);
    __half2 h3 = __floats2half2_rn(b.z, b.w);
    uint4 o;
    o.x = *(const unsigned*)&h0;
    o.y = *(const unsigned*)&h1;
    o.z = *(const unsigned*)&h2;
    o.w = *(const unsigned*)&h3;
    ((uint4*)xh)[i] = o;
}

__device__ __forceinline__ void acc8(uint4 v, float* s) {
    const __half2* h = reinterpret_cast<const __half2*>(&v);
    float2 f0 = __half22float2(h[0]);
    float2 f1 = __half22float2(h[1]);
    float2 f2 = __half22float2(h[2]);
    float2 f3 = __half22float2(h[3]);
    s[0] += f0.x; s[1] += f0.y; s[2] += f1.x; s[3] += f1.y;
    s[4] += f2.x; s[5] += f2.y; s[6] += f3.x; s[7] += f3.y;
}

// ---- gather-mean aggregate: 16 lanes/node, 8 cols/lane ----
// src rows are f16 (hi); src row stride given in uint4 units (16 for Xh, 32 for interleaved H).
// output: f16 hi/lo pair arrays (near-fp32 precision for the GEMM A operand)
__global__ void aggregate_kernel(const __half* __restrict__ xh, int sstride,
                                 const int* __restrict__ csr,
                                 const int* __restrict__ rs, const int* __restrict__ cnt,
                                 const float* __restrict__ inv,
                                 __half* __restrict__ aggh, __half* __restrict__ aggl, int N) {
    int t = blockIdx.x * blockDim.x + threadIdx.x;
    int node = t >> 4;
    int c = t & 15;
    if (node >= N) return;
    int deg = cnt[node];
    int st = rs[node];
    const uint4* x4 = (const uint4*)xh;
    float s[8] = {0.f, 0.f, 0.f, 0.f, 0.f, 0.f, 0.f, 0.f};
    int i = 0;
    for (; i + 4 <= deg; i += 4) {
        int n0 = csr[st + i + 0], n1 = csr[st + i + 1];
        int n2 = csr[st + i + 2], n3 = csr[st + i + 3];
        uint4 v0 = x4[(size_t)n0 * sstride + c];
        uint4 v1 = x4[(size_t)n1 * sstride + c];
        uint4 v2 = x4[(size_t)n2 * sstride + c];
        uint4 v3 = x4[(size_t)n3 * sstride + c];
        acc8(v0, s); acc8(v1, s); acc8(v2, s); acc8(v3, s);
    }
    for (; i < deg; i++) {
        int n0 = csr[st + i];
        uint4 v0 = x4[(size_t)n0 * sstride + c];
        acc8(v0, s);
    }
    float iv = inv[node];
    uint4 oh, ol;
    __half2* ph = (__half2*)&oh;
    __half2* pl = (__half2*)&ol;
#pragma unroll
    for (int jj = 0; jj < 4; jj++) {
        float v0 = s[2 * jj] * iv, v1 = s[2 * jj + 1] * iv;
        __half h0 = __float2half_rn(v0), h1 = __float2half_rn(v1);
        ph[jj] = __halves2half2(h0, h1);
        pl[jj] = __halves2half2(__float2half_rn(v0 - __half2float(h0)),
                                __float2half_rn(v1 - __half2float(h1)));
    }
    ((uint4*)aggh)[(size_t)node * 16 + c] = oh;
    ((uint4*)aggl)[(size_t)node * 16 + c] = ol;
}

// ---- weight pack: fp32 [128k x 128n] -> f16 hi/lo fragment-ordered ----
__global__ void pack_kernel(const float* __restrict__ W1l, const float* __restrict__ W1r,
                            const float* __restrict__ W2l, const float* __restrict__ W2r,
                            const float* __restrict__ Wf, unsigned short* __restrict__ pw) {
    int idx = blockIdx.x * blockDim.x + threadIdx.x;
    if (idx >= 5 * 2048) return;
    int w = idx >> 11;
    int r = idx & 2047;
    int ks = r >> 9;
    int t = (r >> 6) & 7;
    int lane = r & 63;
    int q = lane >> 4, n = lane & 15;
    const float* W = (w == 0) ? W1l : (w == 1) ? W1r : (w == 2) ? W2l : (w == 3) ? W2r : Wf;
    unsigned short* dh = pw + (size_t)w * 32768;
    unsigned short* dl = dh + 16384;
    int off = ((ks * 8 + t) * 64 + lane) * 8;
#pragma unroll
    for (int j = 0; j < 8; j++) {
        float v = W[(size_t)(ks * 32 + q * 8 + j) * D + t * 16 + n];
        __half hb = __float2half_rn(v);
        dh[off + j] = __half_as_ushort(hb);
        dl[off + j] = __half_as_ushort(__float2half_rn(v - __half2float(hb)));
    }
}

__device__ __forceinline__ void split_f16(const float* v, uint4& hi, uint4& lo) {
    __half2* ph = (__half2*)&hi;
    __half2* pl = (__half2*)&lo;
#pragma unroll
    for (int jj = 0; jj < 4; jj++) {
        __half h0 = __float2half_rn(v[2 * jj]);
        __half h1 = __float2half_rn(v[2 * jj + 1]);
        ph[jj] = __halves2half2(h0, h1);
        pl[jj] = __halves2half2(__float2half_rn(v[2 * jj] - __half2float(h0)),
                                __float2half_rn(v[2 * jj + 1] - __half2float(h1)));
    }
}

// ---- full-row-wave streaming MFMA GEMM ----
// block = 4 waves, each wave = 16 rows x 128 cols. grid = ceil(N/64). K=256 (agg|x-or-h).
// LAYER==1: A1 = fp32 x (in-register split); writes h1 row-interleaved (hi[128]|lo[128]) to Hout.
// LAYER==2: A1 = interleaved H (reads own rows, hoisted); fused FC; writes fp32 out in place.
template <int LAYER>
__global__ __launch_bounds__(256) void mfma_gemm(
        const uint4* __restrict__ Agh, const uint4* __restrict__ Agl,  // stride 16 uint4/row
        const float* __restrict__ Xf,                                  // LAYER==1 source
        const uint4* Hio,                                              // LAYER==2 source (stride 32)
        const uint4* __restrict__ W0h, const uint4* __restrict__ W0l,
        const uint4* __restrict__ W1h, const uint4* __restrict__ W1l,
        const float* __restrict__ bias,
        const uint4* __restrict__ W2h, const uint4* __restrict__ W2l,
        const float* __restrict__ bias2,
        float* out, __half* Hout, int N) {
    __shared__ __half Hs[(LAYER == 2) ? 4 * 2 * 16 * HLD : 4];

    const int tid = threadIdx.x;
    const int lane = tid & 63;
    const int wave = tid >> 6;
    const int c = lane & 15;
    const int q = lane >> 4;
    const int R = blockIdx.x * 64 + wave * 16;
    int row0 = R + c;
    if (row0 >= N) row0 = N - 1;

    // --- batch-load all A fragments (one latency exposure) ---
    uint4 Ah_[8], Al_[8];
    const size_t rb16 = (size_t)row0 * 16 + q;
#pragma unroll
    for (int kl = 0; kl < 4; kl++) {
        Ah_[kl] = Agh[rb16 + kl * 4];
        Al_[kl] = Agl[rb16 + kl * 4];
    }
    if (LAYER == 1) {
        const float4* xf4 = (const float4*)Xf;
        const size_t xb = (size_t)row0 * 32 + q * 2;
        float4 xa[8];
#pragma unroll
        for (int kl = 0; kl < 4; kl++) {
            xa[2 * kl] = xf4[xb + kl * 8];
            xa[2 * kl + 1] = xf4[xb + kl * 8 + 1];
        }
#pragma unroll
        for (int kl = 0; kl < 4; kl++) {
            float v[8] = {xa[2 * kl].x, xa[2 * kl].y, xa[2 * kl].z, xa[2 * kl].w,
                          xa[2 * kl + 1].x, xa[2 * kl + 1].y, xa[2 * kl + 1].z, xa[2 * kl + 1].w};
            split_f16(v, Ah_[4 + kl], Al_[4 + kl]);
        }
    } else {
        const size_t rb32 = (size_t)row0 * 32 + q;
#pragma unroll
        for (int kl = 0; kl < 4; kl++) {
            Ah_[4 + kl] = Hio[rb32 + kl * 4];
            Al_[4 + kl] = Hio[rb32 + 16 + kl * 4];
        }
    }

    f32x4 acc[8];
#pragma unroll
    for (int t = 0; t < 8; t++)
#pragma unroll
        for (int r = 0; r < 4; r++) acc[t][r] = 0.0f;

#pragma unroll
    for (int ks = 0; ks < 8; ks++) {
        const uint4* Wh = ((ks < 4) ? W0h : W1h) + (size_t)(ks & 3) * 512 + lane;
        const uint4* Wl = ((ks < 4) ? W0l : W1l) + (size_t)(ks & 3) * 512 + lane;
        f16x8 ah = __builtin_bit_cast(f16x8, Ah_[ks]);
        f16x8 al = __builtin_bit_cast(f16x8, Al_[ks]);
#pragma unroll
        for (int t = 0; t < 8; t++) {
            f16x8 bh = __builtin_bit_cast(f16x8, Wh[t * 64]);
            f16x8 bl = __builtin_bit_cast(f16x8, Wl[t * 64]);
            acc[t] = __builtin_amdgcn_mfma_f32_16x16x32_f16(ah, bh, acc[t], 0, 0, 0);
            acc[t] = __builtin_amdgcn_mfma_f32_16x16x32_f16(al, bh, acc[t], 0, 0, 0);
            acc[t] = __builtin_amdgcn_mfma_f32_16x16x32_f16(ah, bl, acc[t], 0, 0, 0);
        }
    }

    // bias + row L2-norm (whole row lives in this wave: 16-lane shfl reduce) + relu
#pragma unroll
    for (int t = 0; t < 8; t++) {
        float bv = bias[t * 16 + c];
#pragma unroll
        for (int r = 0; r < 4; r++) acc[t][r] += bv;
    }
#pragma unroll
    for (int r = 0; r < 4; r++) {
        float v = 0.0f;
#pragma unroll
        for (int t = 0; t < 8; t++) v += acc[t][r] * acc[t][r];
        v += __shfl_xor(v, 1, 16);
        v += __shfl_xor(v, 2, 16);
        v += __shfl_xor(v, 4, 16);
        v += __shfl_xor(v, 8, 16);
        float rn = 1.0f / fmaxf(sqrtf(v), 1e-12f);
#pragma unroll
        for (int t = 0; t < 8; t++) acc[t][r] = fmaxf(acc[t][r] * rn, 0.0f);
    }

    if (LAYER == 1) {
        // write h1 row-interleaved: per row, halfs [0..127]=hi, [128..255]=lo
#pragma unroll
        for (int t = 0; t < 8; t++)
#pragma unroll
            for (int r = 0; r < 4; r++) {
                int row = R + q * 4 + r;
                if (row < N) {
                    float v = acc[t][r];
                    __half h = __float2half_rn(v);
                    size_t base = (size_t)row * 256;
                    Hout[base + t * 16 + c] = h;
                    Hout[base + 128 + t * 16 + c] = __float2half_rn(v - __half2float(h));
                }
            }
        return;
    }

    // fused FC: stage h (f16 hi/lo) into this wave's private LDS region
    __half* hh = &Hs[wave * (2 * 16 * HLD)];
    __half* hl = hh + 16 * HLD;
#pragma unroll
    for (int t = 0; t < 8; t++)
#pragma unroll
        for (int r = 0; r < 4; r++) {
            int m = q * 4 + r;
            float v = acc[t][r];
            __half h = __float2half_rn(v);
            hh[m * HLD + t * 16 + c] = h;
            hl[m * HLD + t * 16 + c] = __float2half_rn(v - __half2float(h));
        }
    __syncthreads();

    uint4 a2h_[4], a2l_[4];
#pragma unroll
    for (int k2 = 0; k2 < 4; k2++) {
        a2h_[k2] = *(const uint4*)&hh[c * HLD + k2 * 32 + q * 8];
        a2l_[k2] = *(const uint4*)&hl[c * HLD + k2 * 32 + q * 8];
    }

    f32x4 acc2[8];
#pragma unroll
    for (int t = 0; t < 8; t++) {
        float bv = bias2[t * 16 + c];
#pragma unroll
        for (int r = 0; r < 4; r++) acc2[t][r] = bv;
    }
#pragma unroll
    for (int k2 = 0; k2 < 4; k2++) {
        const uint4* Wh = W2h + (size_t)k2 * 512 + lane;
        const uint4* Wl = W2l + (size_t)k2 * 512 + lane;
        f16x8 ah = __builtin_bit_cast(f16x8, a2h_[k2]);
        f16x8 al = __builtin_bit_cast(f16x8, a2l_[k2]);
#pragma unroll
        for (int t = 0; t < 8; t++) {
            f16x8 bh = __builtin_bit_cast(f16x8, Wh[t * 64]);
            f16x8 bl = __builtin_bit_cast(f16x8, Wl[t * 64]);
            acc2[t] = __builtin_amdgcn_mfma_f32_16x16x32_f16(ah, bh, acc2[t], 0, 0, 0);
            acc2[t] = __builtin_amdgcn_mfma_f32_16x16x32_f16(al, bh, acc2[t], 0, 0, 0);
            acc2[t] = __builtin_amdgcn_mfma_f32_16x16x32_f16(ah, bl, acc2[t], 0, 0, 0);
        }
    }

#pragma unroll
    for (int t = 0; t < 8; t++)
#pragma unroll
        for (int r = 0; r < 4; r++) {
            int row = R + q * 4 + r;
            if (row < N) out[(size_t)row * D + t * 16 + c] = acc2[t][r];
        }
}

extern "C" void kernel_launch(void* const* d_in, const int* in_sizes, int n_in,
                              void* d_out, int out_size, void* d_ws, size_t ws_size,
                              hipStream_t stream) {
    const float* x   = (const float*)d_in[0];
    const int*   ei  = (const int*)d_in[1];
    const float* W1l = (const float*)d_in[2];
    const float* b1  = (const float*)d_in[3];
    const float* W1r = (const float*)d_in[4];
    const float* W2l = (const float*)d_in[5];
    const float* b2  = (const float*)d_in[6];
    const float* W2r = (const float*)d_in[7];
    const float* Wf  = (const float*)d_in[8];
    const float* bf  = (const float*)d_in[9];
    float* out = (float*)d_out;

    int N = in_sizes[0] / D;
    int E = in_sizes[1] / 2;

    // ws (~41.9 MB, same budget as the previously-passing kernel):
    //   Agh[N*D] h | Agl[N*D] h | Xh[N*D] h | inv[N] f | rs[N] i | cnt[N] i | cursor[N] i |
    //   bsum[256] i | csr[E] i | pw[5*32768] ush
    // h1 (f16 hi/lo, row-interleaved) lives in d_out between the layer-1 and layer-2 GEMMs.
    __half* Agh = (__half*)d_ws;
    __half* Agl = Agh + (size_t)N * D;
    __half* Xh  = Agl + (size_t)N * D;
    float* inv  = (float*)(Xh + (size_t)N * D);
    int*   rs     = (int*)(inv + N);
    int*   cnt    = rs + N;
    int*   cursor = cnt + N;
    int*   bsum   = cursor + N;
    int*   csr    = bsum + 256;
    unsigned short* pw = (unsigned short*)(csr + E);
    unsigned short* p1lh = pw + 0 * 32768, *p1ll = p1lh + 16384;
    unsigned short* p1rh = pw + 1 * 32768, *p1rl = p1rh + 16384;
    unsigned short* p2lh = pw + 2 * 32768, *p2ll = p2lh + 16384;
    unsigned short* p2rh = pw + 3 * 32768, *p2rl = p2rh + 16384;
    unsigned short* pfh  = pw + 4 * 32768, *pfl  = pfh + 16384;

    __half* H1 = (__half*)d_out;  // interleaved h1: row*256 halfs (hi 128 | lo 128)

    int nb = (N + SCAN_B - 1) / SCAN_B;

    hipMemsetAsync(cnt, 0, (size_t)N * sizeof(int), stream);
    pack_kernel<<<40, 256, 0, stream>>>(W1l, W1r, W2l, W2r, Wf, pw);
    int n8 = N * 16;
    cvt_half_kernel<<<(n8 + 255) / 256, 256, 0, stream>>>(x, Xh, n8);
    count_kernel<<<(E + 255) / 256, 256, 0, stream>>>(ei, E, cnt);
    scan_pass1<<<nb, SCAN_B, 0, stream>>>(cnt, rs, bsum, N);
    scan_pass2<<<1, SCAN_B, 0, stream>>>(bsum, nb);
    scan_pass3<<<nb, SCAN_B, 0, stream>>>(rs, cursor, bsum, cnt, inv, N);
    fill_kernel<<<(E + 255) / 256, 256, 0, stream>>>(ei, E, cursor, csr);

    int agg_blocks = (N * 16 + 255) / 256;
    int gemm_blocks = (N + 63) / 64;

    // layer 1: agg from Xh; GEMM reads (agg | fp32 x), writes interleaved h1 into d_out
    aggregate_kernel<<<agg_blocks, 256, 0, stream>>>(Xh, 16, csr, rs, cnt, inv, Agh, Agl, N);
    mfma_gemm<1><<<gemm_blocks, 256, 0, stream>>>(
        (const uint4*)Agh, (const uint4*)Agl, x, nullptr,
        (const uint4*)p1lh, (const uint4*)p1ll, (const uint4*)p1rh, (const uint4*)p1rl, b1,
        nullptr, nullptr, nullptr, nullptr, H1, N);

    // layer 2: agg from h1-hi (stride 32 uint4); GEMM + fused FC, writes fp32 out in place
    aggregate_kernel<<<agg_blocks, 256, 0, stream>>>(H1, 32, csr, rs, cnt, inv, Agh, Agl, N);
    mfma_gemm<2><<<gemm_blocks, 256, 0, stream>>>(
        (const uint4*)Agh, (const uint4*)Agl, nullptr, (const uint4*)d_out,
        (const uint4*)p2lh, (const uint4*)p2ll, (const uint4*)p2rh, (const uint4*)p2rl, b2,
        (const uint4*)pfh, (const uint4*)pfl, bf, out, nullptr, N);
}